// Round 6
// baseline (809.007 us; speedup 1.0000x reference)
//
#include <hip/hip_runtime.h>
#include <hip/hip_fp16.h>

// ---------------------------------------------------------------------------
// GCN 2-layer (PyG GCNConv) on MI355X — R20 (= R19 resubmit).
// R19 bench died with "container failed twice" (no counters) — audit found
// no hang candidates (all loops bounded, atomic scatter provably in-range);
// the only graph-capture-ambiguous call was hipMemsetAsync inside
// kernel_launch. R20 replaces it with a k_zero kernel (int2 zeros, ~0.3us).
// Everything else byte-identical to R19. If this fails too -> infra.
// Theory/prediction unchanged from R19:
//   Direct per-node counting-sort CSR build (k_zero -> k_deg -> k_scan_off
//   -> k_scat) replaces the 5-kernel bucket build (which wrote+read 25.6MB
//   binned and ran 196-block latency-starved grids). dinv array deleted;
//   consumers compute rsqrtf(1+fsum[node]) inline. agg1/agg2/gemm are
//   EXACTLY R16's proven bodies (52.1us agg1).
// Predict: agg1 ~52 (top, FETCH ~157MB); k_scat ~15-20; k_deg ~10;
// total 287.5 -> ~245-260us; absmax ~9.77e-4.
// Failure signature: k_scat/k_deg in top-5 above 52us => atomic throughput
// worse than modeled => revert to bucket build.
// ---------------------------------------------------------------------------

typedef _Float16 f16x8 __attribute__((ext_vector_type(8)));
typedef float    f32x4 __attribute__((ext_vector_type(4)));

// ---------------- CSR build (direct counting sort) ----------------

// Zero cnt[N] + fsum[N] (contiguous): 2N ints as N int2 stores.
__global__ __launch_bounds__(256) void k_zero(int2* __restrict__ cz, int N) {
    int i = blockIdx.x * 256 + threadIdx.x;
    if (i < N) cz[i] = make_int2(0, 0);
}

// Per-node degree count + edge-weight sum. 1 int4 per thread, 782 blocks.
__global__ __launch_bounds__(1024) void k_deg(const int* __restrict__ col,
                                              const float* __restrict__ ea,
                                              int* __restrict__ cnt,
                                              float* __restrict__ fsum, int E4) {
    int idx = blockIdx.x * 1024 + threadIdx.x;
    if (idx < E4) {
        int4   c = ((const int4*)col)[idx];
        float4 w = ((const float4*)ea)[idx];
        atomicAdd(&cnt[c.x], 1);  atomicAdd(&fsum[c.x], w.x);
        atomicAdd(&cnt[c.y], 1);  atomicAdd(&fsum[c.y], w.y);
        atomicAdd(&cnt[c.z], 1);  atomicAdd(&fsum[c.z], w.z);
        atomicAdd(&cnt[c.w], 1);  atomicAdd(&fsum[c.w], w.w);
    }
}

// One 1024-thread block: exclusive scan of cnt[0..N) -> offset[0..N].
// Thread t owns a contiguous chunk; chunk sums scanned in LDS (Hillis-Steele).
__global__ __launch_bounds__(1024) void k_scan_off(const int* __restrict__ cnt,
                                                   int* __restrict__ offset,
                                                   int N, int E) {
    __shared__ int A[2][1024];
    int t = threadIdx.x;
    int per = (N + 1023) >> 10;
    int s0 = t * per;
    int s1 = min(s0 + per, N);
    int sum = 0;
    for (int i = s0; i < s1; ++i) sum += cnt[i];
    A[0][t] = sum;
    __syncthreads();
    int src = 0;
    for (int off = 1; off < 1024; off <<= 1) {
        A[1 - src][t] = A[src][t] + ((t >= off) ? A[src][t - off] : 0);
        src ^= 1;
        __syncthreads();
    }
    int base = (t > 0) ? A[src][t - 1] : 0;
    for (int i = s0; i < s1; ++i) {
        offset[i] = base;
        base += cnt[i];
    }
    if (t == 0) offset[N] = E;
}

// Direct scatter to final csr position. old = atomicAdd(cnt,-1) in [deg..1]
// -> p = offset[c+1]-old in [offset[c]..offset[c+1]-1], unique per edge.
// csr[p] = f16bits(w)[14:0] << 17 | row   (w in [0,1) -> sign bit 0).
__global__ __launch_bounds__(1024) void k_scat(const int* __restrict__ ei,
                                               const float* __restrict__ ea,
                                               const int* __restrict__ offset,
                                               int* __restrict__ cnt,
                                               unsigned* __restrict__ csr,
                                               int E, int E4) {
    int idx = blockIdx.x * 1024 + threadIdx.x;
    if (idx < E4) {
        int4   r = ((const int4*)ei)[idx];
        int4   c = ((const int4*)(ei + E))[idx];
        float4 w = ((const float4*)ea)[idx];
        int old, p;
        unsigned hb;
        old = atomicAdd(&cnt[c.x], -1); p = offset[c.x + 1] - old;
        hb = (unsigned)__half_as_ushort(__float2half_rn(w.x)) & 0x7FFFu;
        csr[p] = (hb << 17) | (unsigned)r.x;
        old = atomicAdd(&cnt[c.y], -1); p = offset[c.y + 1] - old;
        hb = (unsigned)__half_as_ushort(__float2half_rn(w.y)) & 0x7FFFu;
        csr[p] = (hb << 17) | (unsigned)r.y;
        old = atomicAdd(&cnt[c.z], -1); p = offset[c.z + 1] - old;
        hb = (unsigned)__half_as_ushort(__float2half_rn(w.z)) & 0x7FFFu;
        csr[p] = (hb << 17) | (unsigned)r.z;
        old = atomicAdd(&cnt[c.w], -1); p = offset[c.w + 1] - old;
        hb = (unsigned)__half_as_ushort(__float2half_rn(w.w)) & 0x7FFFu;
        csr[p] = (hb << 17) | (unsigned)r.w;
    }
}

// ---------------- dense compute (R16 body; dinv -> rsqrt(1+fsum)) ---------

__global__ __launch_bounds__(256) void k_gemm_mfma(const float* __restrict__ x,
                                                   const float* __restrict__ W1,
                                                   const float* __restrict__ fsum,
                                                   __half* __restrict__ hs, int n) {
    __shared__ _Float16 xh[64][136];
    __shared__ _Float16 wTh[64][136];
    int t = threadIdx.x;
    int nodeBase = blockIdx.x * 64;

    for (int i = t; i < 2048; i += 256) {
        int r = i >> 5, c4 = i & 31;
        int node = nodeBase + r;
        float4 v = make_float4(0.f, 0.f, 0.f, 0.f);
        if (node < n) v = ((const float4*)x)[node * 32 + c4];
        _Float16* dst = &xh[r][c4 * 4];
        dst[0] = (_Float16)v.x; dst[1] = (_Float16)v.y;
        dst[2] = (_Float16)v.z; dst[3] = (_Float16)v.w;
    }
    for (int i = t; i < 2048; i += 256) {
        int k = i >> 4, c4 = i & 15;
        float4 v = ((const float4*)W1)[k * 16 + c4];
        wTh[c4 * 4 + 0][k] = (_Float16)v.x;
        wTh[c4 * 4 + 1][k] = (_Float16)v.y;
        wTh[c4 * 4 + 2][k] = (_Float16)v.z;
        wTh[c4 * 4 + 3][k] = (_Float16)v.w;
    }
    __syncthreads();

    int w = t >> 6, lane = t & 63;
    int m = lane & 15, quad = lane >> 4;

    f32x4 acc[4] = {{0.f,0.f,0.f,0.f},{0.f,0.f,0.f,0.f},
                    {0.f,0.f,0.f,0.f},{0.f,0.f,0.f,0.f}};
#pragma unroll
    for (int ks = 0; ks < 128; ks += 32) {
        f16x8 a = *(const f16x8*)&xh[w * 16 + m][ks + quad * 8];
#pragma unroll
        for (int ct = 0; ct < 4; ++ct) {
            f16x8 bfr = *(const f16x8*)&wTh[ct * 16 + m][ks + quad * 8];
            acc[ct] = __builtin_amdgcn_mfma_f32_16x16x32_f16(a, bfr, acc[ct], 0, 0, 0);
        }
    }

#pragma unroll
    for (int reg = 0; reg < 4; ++reg) {
        int node = nodeBase + w * 16 + quad * 4 + reg;
        if (node < n) {
            float dv = rsqrtf(1.0f + fsum[node]);
#pragma unroll
            for (int ct = 0; ct < 4; ++ct) {
                float v = acc[ct][reg] * dv;
                hs[(size_t)node * 64 + ct * 16 + m] = __float2half_rn(v);
            }
        }
    }
}

// ---------------- DPP reduce helpers (hardware-verified in R16) ----------

__device__ __forceinline__ float dpp_ror8(float x) {
    return __int_as_float(__builtin_amdgcn_update_dpp(
        0, __float_as_int(x), 0x128, 0xF, 0xF, true));
}
template<int CTRL>
__device__ __forceinline__ float dpp_mov(float x) {
    return __int_as_float(__builtin_amdgcn_update_dpp(
        0, __float_as_int(x), CTRL, 0xF, 0xF, true));
}
__device__ __forceinline__ float swz_xor16(float x) {
    return __int_as_float(__builtin_amdgcn_ds_swizzle(__float_as_int(x), 0x401F));
}

// ---------------- agg1 (R16 body; dinv -> rsqrt(1+fsum)) ----------------

__global__ __launch_bounds__(256) void k_agg1(const __half* __restrict__ hs,
                                              const int* __restrict__ offset,
                                              const unsigned* __restrict__ csr,
                                              const float* __restrict__ fsum,
                                              const float* __restrict__ b1,
                                              const float* __restrict__ W2,
                                              float* __restrict__ h2s, int n) {
    int wid  = __builtin_amdgcn_readfirstlane(
                   (int)((blockIdx.x * blockDim.x + threadIdx.x) >> 6));
    int lane = threadIdx.x & 63;
    if (wid >= n) return;
    int off0 = __builtin_amdgcn_readfirstlane(offset[wid]);
    int off1 = __builtin_amdgcn_readfirstlane(offset[wid + 1]);
    int g = lane >> 3, s = lane & 7;
    unsigned sbyte = (unsigned)s << 4;          // s * 16 bytes
    const char* hsB = (const char*)hs;

    float acc[8] = {0.f, 0.f, 0.f, 0.f, 0.f, 0.f, 0.f, 0.f};

    {   // self loop (weight 1)
        f16x8 v = *(const f16x8*)(hsB + (((unsigned)wid) << 7) + sbyte);
        if (g == 0) {
#pragma unroll
            for (int k = 0; k < 8; ++k) acc[k] += (float)v[k];
        }
    }

    for (int j = off0; j < off1; j += 32) {
        int   i0 = j + g,      i1 = j + 8 + g,  i2 = j + 16 + g, i3 = j + 24 + g;
        bool  k0 = i0 < off1,  k1 = i1 < off1,  k2 = i2 < off1,  k3 = i3 < off1;
        unsigned eA = csr[k0 ? i0 : off1 - 1];
        unsigned eB = csr[k1 ? i1 : off1 - 1];
        unsigned eC = csr[k2 ? i2 : off1 - 1];
        unsigned eD = csr[k3 ? i3 : off1 - 1];
        f16x8 vA = *(const f16x8*)(hsB + ((eA & 0x1FFFFu) << 7) + sbyte);
        f16x8 vB = *(const f16x8*)(hsB + ((eB & 0x1FFFFu) << 7) + sbyte);
        f16x8 vC = *(const f16x8*)(hsB + ((eC & 0x1FFFFu) << 7) + sbyte);
        f16x8 vD = *(const f16x8*)(hsB + ((eD & 0x1FFFFu) << 7) + sbyte);
        float wA = k0 ? (float)__ushort_as_half((unsigned short)(eA >> 17)) : 0.f;
        float wB = k1 ? (float)__ushort_as_half((unsigned short)(eB >> 17)) : 0.f;
        float wC = k2 ? (float)__ushort_as_half((unsigned short)(eC >> 17)) : 0.f;
        float wD = k3 ? (float)__ushort_as_half((unsigned short)(eD >> 17)) : 0.f;
#pragma unroll
        for (int k = 0; k < 8; ++k) {
            acc[k] += wA * (float)vA[k];
            acc[k] += wB * (float)vB[k];
            acc[k] += wC * (float)vC[k];
            acc[k] += wD * (float)vD[k];
        }
    }

    // reduce over groups (lane bits 3,4,5): DPP ror8 + swizzle xor16 + shfl32
#pragma unroll
    for (int k = 0; k < 8; ++k) {
        float t = acc[k];
        t += dpp_ror8(t);
        t += swz_xor16(t);
        t += __shfl_xor(t, 32);
        acc[k] = t;
    }

    float di = rsqrtf(1.0f + fsum[wid]);
    float4 bA = ((const float4*)b1)[s * 2], bB = ((const float4*)b1)[s * 2 + 1];
    float4 wA = ((const float4*)W2)[s * 2], wB = ((const float4*)W2)[s * 2 + 1];
    float p = 0.f;
    p += fmaxf(di * acc[0] + bA.x, 0.f) * wA.x;
    p += fmaxf(di * acc[1] + bA.y, 0.f) * wA.y;
    p += fmaxf(di * acc[2] + bA.z, 0.f) * wA.z;
    p += fmaxf(di * acc[3] + bA.w, 0.f) * wA.w;
    p += fmaxf(di * acc[4] + bB.x, 0.f) * wB.x;
    p += fmaxf(di * acc[5] + bB.y, 0.f) * wB.y;
    p += fmaxf(di * acc[6] + bB.z, 0.f) * wB.z;
    p += fmaxf(di * acc[7] + bB.w, 0.f) * wB.w;
    // reduce over s (lane bits 0,1,2): pure DPP
    p += dpp_mov<0xB1>(p);    // quad_perm [1,0,3,2] == xor 1
    p += dpp_mov<0x4E>(p);    // quad_perm [2,3,0,1] == xor 2
    p += dpp_mov<0x141>(p);   // row_half_mirror == xor 4 after 1,2 reduced
    if (lane == 0) h2s[wid] = di * p;
}

// ---------------- agg2 (R16 body; dinv -> rsqrt(1+fsum)) ----------------

__global__ __launch_bounds__(256) void k_agg2(const float* __restrict__ h2s,
                                              const int* __restrict__ offset,
                                              const unsigned* __restrict__ csr,
                                              const float* __restrict__ fsum,
                                              const float* __restrict__ b2,
                                              float* __restrict__ out, int n) {
    int wid = __builtin_amdgcn_readfirstlane((int)((blockIdx.x * blockDim.x + threadIdx.x) >> 6));
    int lane = threadIdx.x & 63;
    if (wid >= n) return;
    int off0 = __builtin_amdgcn_readfirstlane(offset[wid]);
    int off1 = __builtin_amdgcn_readfirstlane(offset[wid + 1]);
    float di = rsqrtf(1.0f + fsum[wid]);
    float p = 0.f;
    for (int e = off0 + lane; e < off1; e += 64) {
        unsigned ed = csr[e];
        p += (float)__ushort_as_half((unsigned short)(ed >> 17)) * h2s[ed & 0x1FFFF];
    }
#pragma unroll
    for (int s = 32; s > 0; s >>= 1) p += __shfl_xor(p, s);
    if (lane == 0) out[wid] = di * (p + h2s[wid]) + b2[0];
}

extern "C" void kernel_launch(void* const* d_in, const int* in_sizes, int n_in,
                              void* d_out, int out_size, void* d_ws, size_t ws_size,
                              hipStream_t stream) {
    const float* x  = (const float*)d_in[0];
    const int*   ei = (const int*)  d_in[1];
    const float* ea = (const float*)d_in[2];
    const float* W1 = (const float*)d_in[3];
    const float* b1 = (const float*)d_in[4];
    const float* W2 = (const float*)d_in[5];
    const float* b2 = (const float*)d_in[6];
    float* out = (float*)d_out;

    const int N  = in_sizes[0] / 128;   // 100000 (must be <= 131072)
    const int E  = in_sizes[2];         // 3200000
    const int E4 = E / 4;

    char* p = (char*)d_ws;
    auto alloc = [&](size_t bytes) -> void* {
        void* r = (void*)p;
        p += (bytes + 255) & ~(size_t)255;
        return r;
    };
    int*       cnt    = (int*)      alloc((size_t)N * 8);   // cnt[N] + fsum[N]
    float*     fsum   = (float*)(cnt + N);
    int*       offset = (int*)      alloc((size_t)(N + 1) * 4);
    unsigned*  csr    = (unsigned*) alloc((size_t)E * 4);
    __half*    hs     = (__half*)   alloc((size_t)N * 64 * 2);
    float*     h2s    = (float*)    alloc((size_t)N * 4);

    const int nbZ     = (N + 255) / 256;         // 391
    const int nbE     = (E4 + 1023) / 1024;      // 782
    const int nb_gemm = (N + 63) / 64;           // 1563
    const int nb_wave = (N * 64 + 255) / 256;    // one 64-wide wave per node

    k_zero<<<nbZ, 256, 0, stream>>>((int2*)cnt, N);
    k_deg<<<nbE, 1024, 0, stream>>>(ei + E, ea, cnt, fsum, E4);
    k_scan_off<<<1, 1024, 0, stream>>>(cnt, offset, N, E);
    k_gemm_mfma<<<nb_gemm, 256, 0, stream>>>(x, W1, fsum, hs, N);
    k_scat<<<nbE, 1024, 0, stream>>>(ei, ea, offset, cnt, csr, E, E4);
    k_agg1<<<nb_wave, 256, 0, stream>>>(hs, offset, csr, fsum, b1, W2, h2s, N);
    k_agg2<<<nb_wave, 256, 0, stream>>>(h2s, offset, csr, fsum, b2, out, N);
}

// Round 7
// 305.861 us; speedup vs baseline: 2.6450x; 2.6450x over previous
//
#include <hip/hip_runtime.h>
#include <hip/hip_fp16.h>

// ---------------------------------------------------------------------------
// GCN 2-layer (PyG GCNConv) on MI355X — R21.
// R20 post-mortem: direct counting-sort build DIED on global atomics
// (k_deg 294us, VALU 0.2%, WRITE 199MB: 12.8M device-scope random-line RMWs
// serialize at the cross-XCD coherence point). LEDGER: never use >=1M
// random global atomics on MI355X; the bucket build's LDS cursors exist to
// avoid exactly this. R19's infra failure was transient (k_zero ran fine).
// R21 = full revert to R16 (287.5us best: bucket build + 52.1us agg1) with
// ONE confined agg1 delta, doubling as a fabric-vs-MLP probe:
//   agg1 moves 157MB at 3.0TB/s with only 4 gathers in flight/wave. R15's
//   8-deep attempt spilled (helper fn + arrays). R21 redoes it CLEANLY:
//   deg-dispatched single-pass 64-slot gather, inline, individually-named
//   scalars e0..e7 / v0..v7 (no arrays -> no scratch), deg>64 fallback
//   (P~3e-7), deg<=64 single pass with 8 outstanding gathers.
// Predict: if MLP-limited agg1 -> ~40-44us (hbm_gbps -> ~3.8-4TB/s, FETCH
// ~157MB, WRITE ~0.8MB, VGPR 64-76), total ~276. If flat ~52 with no spill
// -> random-gather fabric ceiling confirmed; agg1 done, build is next.
// Failure signature: WRITE_SIZE >> 1MB => spill => freeze agg1 at R16 form.
// ---------------------------------------------------------------------------

#define BSHIFT 9
#define BSIZE 512            // nodes per bucket
#define NBUCKET 256          // max buckets (requires N <= 131072)

typedef _Float16 f16x8 __attribute__((ext_vector_type(8)));
typedef float    f32x4 __attribute__((ext_vector_type(4)));

// ---------------- CSR build (identical to R16) ----------------

__global__ __launch_bounds__(1024) void k_hist(const int* __restrict__ col,
                                               int* __restrict__ hist, int E4) {
    __shared__ int h[NBUCKET];
    int t = threadIdx.x, bl = blockIdx.x;
    if (t < NBUCKET) h[t] = 0;
    __syncthreads();
#pragma unroll
    for (int i = 0; i < 4; ++i) {
        int idx = bl * 4096 + i * 1024 + t;
        if (idx < E4) {
            int4 c = ((const int4*)col)[idx];
            atomicAdd(&h[c.x >> BSHIFT], 1);
            atomicAdd(&h[c.y >> BSHIFT], 1);
            atomicAdd(&h[c.z >> BSHIFT], 1);
            atomicAdd(&h[c.w >> BSHIFT], 1);
        }
    }
    __syncthreads();
    if (t < NBUCKET) hist[bl * NBUCKET + t] = h[t];
}

__global__ __launch_bounds__(256) void k_scan_bucket(const int* __restrict__ hist,
                                                     int* __restrict__ histS,
                                                     int* __restrict__ tot, int nbl) {
    __shared__ int A[2][256];
    int b = blockIdx.x, t = threadIdx.x;
    A[0][t] = (t < nbl) ? hist[t * NBUCKET + b] : 0;
    __syncthreads();
    int src = 0;
    for (int off = 1; off < 256; off <<= 1) {
        A[1 - src][t] = A[src][t] + ((t >= off) ? A[src][t - off] : 0);
        src ^= 1;
        __syncthreads();
    }
    if (t < nbl) histS[b * nbl + t] = (t > 0) ? A[src][t - 1] : 0;
    if (t == 0) tot[b] = A[src][nbl - 1];
}

__global__ __launch_bounds__(256) void k_scan_tot(const int* __restrict__ tot,
                                                  int* __restrict__ base) {
    __shared__ int A[2][NBUCKET];
    int t = threadIdx.x;
    A[0][t] = tot[t];
    __syncthreads();
    int src = 0;
    for (int off = 1; off < NBUCKET; off <<= 1) {
        A[1 - src][t] = A[src][t] + ((t >= off) ? A[src][t - off] : 0);
        src ^= 1;
        __syncthreads();
    }
    base[t] = (t > 0) ? A[src][t - 1] : 0;
    if (t == 255) base[NBUCKET] = A[src][255];
}

__global__ __launch_bounds__(1024) void k_scatter(const int* __restrict__ ei,
                                                  const float* __restrict__ ea,
                                                  const int* __restrict__ histS,
                                                  const int* __restrict__ base,
                                                  int2* __restrict__ binned,
                                                  int E, int E4, int nbl) {
    __shared__ int cur[NBUCKET];
    int t = threadIdx.x, bl = blockIdx.x;
    if (t < NBUCKET) cur[t] = base[t] + histS[t * nbl + bl];
    __syncthreads();
#pragma unroll
    for (int i = 0; i < 4; ++i) {
        int idx = bl * 4096 + i * 1024 + t;
        if (idx < E4) {
            int4   r = ((const int4*)ei)[idx];
            int4   c = ((const int4*)(ei + E))[idx];
            float4 w = ((const float4*)ea)[idx];
            int p;
            p = atomicAdd(&cur[c.x >> BSHIFT], 1);
            binned[p] = make_int2(((c.x & (BSIZE - 1)) << 17) | r.x, __float_as_int(w.x));
            p = atomicAdd(&cur[c.y >> BSHIFT], 1);
            binned[p] = make_int2(((c.y & (BSIZE - 1)) << 17) | r.y, __float_as_int(w.y));
            p = atomicAdd(&cur[c.z >> BSHIFT], 1);
            binned[p] = make_int2(((c.z & (BSIZE - 1)) << 17) | r.z, __float_as_int(w.z));
            p = atomicAdd(&cur[c.w >> BSHIFT], 1);
            binned[p] = make_int2(((c.w & (BSIZE - 1)) << 17) | r.w, __float_as_int(w.w));
        }
    }
}

__global__ __launch_bounds__(1024) void k_finalize(const int2* __restrict__ binned,
                                                   const int* __restrict__ base,
                                                   unsigned* __restrict__ csr,
                                                   int* __restrict__ offset,
                                                   float* __restrict__ dinv,
                                                   int N, int E) {
    __shared__ int   cnt[BSIZE];
    __shared__ float fsum[BSIZE];
    __shared__ int   inc[2][BSIZE];
    __shared__ int   cur[BSIZE];
    int b = blockIdx.x, t = threadIdx.x;
    int e0 = base[b], e1 = base[b + 1];
    for (int i = t; i < BSIZE; i += 1024) { cnt[i] = 0; fsum[i] = 0.f; }
    __syncthreads();
    for (int e = e0 + t; e < e1; e += 1024) {
        int2 ed = binned[e];
        unsigned cl = ((unsigned)ed.x) >> 17;
        atomicAdd(&cnt[cl], 1);
        atomicAdd(&fsum[cl], __int_as_float(ed.y));
    }
    __syncthreads();
    for (int i = t; i < BSIZE; i += 1024) inc[0][i] = cnt[i];
    __syncthreads();
    int src = 0;
    for (int off = 1; off < BSIZE; off <<= 1) {
        for (int i = t; i < BSIZE; i += 1024)
            inc[1 - src][i] = inc[src][i] + ((i >= off) ? inc[src][i - off] : 0);
        src ^= 1;
        __syncthreads();
    }
    int nodeBase = b << BSHIFT;
    for (int i = t; i < BSIZE; i += 1024) {
        int ex = (i > 0) ? inc[src][i - 1] : 0;
        cur[i] = e0 + ex;
        int node = nodeBase + i;
        if (node < N) {
            offset[node] = e0 + ex;
            dinv[node]   = rsqrtf(1.0f + fsum[i]);
        }
    }
    if (b == 0 && t == 0) offset[N] = E;
    __syncthreads();
    for (int e = e0 + t; e < e1; e += 1024) {
        int2 ed = binned[e];
        unsigned cl = ((unsigned)ed.x) >> 17;
        unsigned row = ((unsigned)ed.x) & 0x1FFFF;
        unsigned hb = (unsigned)__half_as_ushort(__float2half_rn(__int_as_float(ed.y))) & 0x7FFFu;
        int p = atomicAdd(&cur[cl], 1);
        csr[p] = (hb << 17) | row;
    }
}

// ---------------- dense compute (identical to R16) ----------------

__global__ __launch_bounds__(256) void k_gemm_mfma(const float* __restrict__ x,
                                                   const float* __restrict__ W1,
                                                   const float* __restrict__ dinv,
                                                   __half* __restrict__ hs, int n) {
    __shared__ _Float16 xh[64][136];
    __shared__ _Float16 wTh[64][136];
    int t = threadIdx.x;
    int nodeBase = blockIdx.x * 64;

    for (int i = t; i < 2048; i += 256) {
        int r = i >> 5, c4 = i & 31;
        int node = nodeBase + r;
        float4 v = make_float4(0.f, 0.f, 0.f, 0.f);
        if (node < n) v = ((const float4*)x)[node * 32 + c4];
        _Float16* dst = &xh[r][c4 * 4];
        dst[0] = (_Float16)v.x; dst[1] = (_Float16)v.y;
        dst[2] = (_Float16)v.z; dst[3] = (_Float16)v.w;
    }
    for (int i = t; i < 2048; i += 256) {
        int k = i >> 4, c4 = i & 15;
        float4 v = ((const float4*)W1)[k * 16 + c4];
        wTh[c4 * 4 + 0][k] = (_Float16)v.x;
        wTh[c4 * 4 + 1][k] = (_Float16)v.y;
        wTh[c4 * 4 + 2][k] = (_Float16)v.z;
        wTh[c4 * 4 + 3][k] = (_Float16)v.w;
    }
    __syncthreads();

    int w = t >> 6, lane = t & 63;
    int m = lane & 15, quad = lane >> 4;

    f32x4 acc[4] = {{0.f,0.f,0.f,0.f},{0.f,0.f,0.f,0.f},
                    {0.f,0.f,0.f,0.f},{0.f,0.f,0.f,0.f}};
#pragma unroll
    for (int ks = 0; ks < 128; ks += 32) {
        f16x8 a = *(const f16x8*)&xh[w * 16 + m][ks + quad * 8];
#pragma unroll
        for (int ct = 0; ct < 4; ++ct) {
            f16x8 bfr = *(const f16x8*)&wTh[ct * 16 + m][ks + quad * 8];
            acc[ct] = __builtin_amdgcn_mfma_f32_16x16x32_f16(a, bfr, acc[ct], 0, 0, 0);
        }
    }

#pragma unroll
    for (int reg = 0; reg < 4; ++reg) {
        int node = nodeBase + w * 16 + quad * 4 + reg;
        if (node < n) {
            float dv = dinv[node];
#pragma unroll
            for (int ct = 0; ct < 4; ++ct) {
                float v = acc[ct][reg] * dv;
                hs[(size_t)node * 64 + ct * 16 + m] = __float2half_rn(v);
            }
        }
    }
}

// ---------------- DPP reduce helpers (hardware-verified in R16) ----------

__device__ __forceinline__ float dpp_ror8(float x) {
    return __int_as_float(__builtin_amdgcn_update_dpp(
        0, __float_as_int(x), 0x128, 0xF, 0xF, true));
}
template<int CTRL>
__device__ __forceinline__ float dpp_mov(float x) {
    return __int_as_float(__builtin_amdgcn_update_dpp(
        0, __float_as_int(x), CTRL, 0xF, 0xF, true));
}
__device__ __forceinline__ float swz_xor16(float x) {
    return __int_as_float(__builtin_amdgcn_ds_swizzle(__float_as_int(x), 0x401F));
}

// ---------------- agg1 (R21: inline 8-deep single-pass for deg<=64) ------

__global__ __launch_bounds__(256) void k_agg1(const __half* __restrict__ hs,
                                              const int* __restrict__ offset,
                                              const unsigned* __restrict__ csr,
                                              const float* __restrict__ dinv,
                                              const float* __restrict__ b1,
                                              const float* __restrict__ W2,
                                              float* __restrict__ h2s, int n) {
    int wid  = __builtin_amdgcn_readfirstlane(
                   (int)((blockIdx.x * blockDim.x + threadIdx.x) >> 6));
    int lane = threadIdx.x & 63;
    if (wid >= n) return;
    int off0 = __builtin_amdgcn_readfirstlane(offset[wid]);
    int off1 = __builtin_amdgcn_readfirstlane(offset[wid + 1]);
    int g = lane >> 3, s = lane & 7;
    unsigned sbyte = (unsigned)s << 4;          // s * 16 bytes
    const char* hsB = (const char*)hs;

    float acc[8] = {0.f, 0.f, 0.f, 0.f, 0.f, 0.f, 0.f, 0.f};

    {   // self loop (weight 1)
        f16x8 v = *(const f16x8*)(hsB + (((unsigned)wid) << 7) + sbyte);
        if (g == 0) {
#pragma unroll
            for (int k = 0; k < 8; ++k) acc[k] += (float)v[k];
        }
    }

    int deg = off1 - off0;
    if (deg > 0 && deg <= 64) {
        // single pass, 8 gathers in flight; named scalars only (no spill)
        int i0 = off0 + g;
        int i1 = i0 + 8,  i2 = i0 + 16, i3 = i0 + 24;
        int i4 = i0 + 32, i5 = i0 + 40, i6 = i0 + 48, i7 = i0 + 56;
        bool k0 = i0 < off1, k1 = i1 < off1, k2 = i2 < off1, k3 = i3 < off1;
        bool k4 = i4 < off1, k5 = i5 < off1, k6 = i6 < off1, k7 = i7 < off1;
        int last = off1 - 1;
        unsigned e0 = csr[k0 ? i0 : last];
        unsigned e1 = csr[k1 ? i1 : last];
        unsigned e2 = csr[k2 ? i2 : last];
        unsigned e3 = csr[k3 ? i3 : last];
        unsigned e4 = csr[k4 ? i4 : last];
        unsigned e5 = csr[k5 ? i5 : last];
        unsigned e6 = csr[k6 ? i6 : last];
        unsigned e7 = csr[k7 ? i7 : last];
        f16x8 v0 = *(const f16x8*)(hsB + ((e0 & 0x1FFFFu) << 7) + sbyte);
        f16x8 v1 = *(const f16x8*)(hsB + ((e1 & 0x1FFFFu) << 7) + sbyte);
        f16x8 v2 = *(const f16x8*)(hsB + ((e2 & 0x1FFFFu) << 7) + sbyte);
        f16x8 v3 = *(const f16x8*)(hsB + ((e3 & 0x1FFFFu) << 7) + sbyte);
        f16x8 v4 = *(const f16x8*)(hsB + ((e4 & 0x1FFFFu) << 7) + sbyte);
        f16x8 v5 = *(const f16x8*)(hsB + ((e5 & 0x1FFFFu) << 7) + sbyte);
        f16x8 v6 = *(const f16x8*)(hsB + ((e6 & 0x1FFFFu) << 7) + sbyte);
        f16x8 v7 = *(const f16x8*)(hsB + ((e7 & 0x1FFFFu) << 7) + sbyte);
        float w0 = k0 ? (float)__ushort_as_half((unsigned short)(e0 >> 17)) : 0.f;
        float w1 = k1 ? (float)__ushort_as_half((unsigned short)(e1 >> 17)) : 0.f;
        float w2 = k2 ? (float)__ushort_as_half((unsigned short)(e2 >> 17)) : 0.f;
        float w3 = k3 ? (float)__ushort_as_half((unsigned short)(e3 >> 17)) : 0.f;
        float w4 = k4 ? (float)__ushort_as_half((unsigned short)(e4 >> 17)) : 0.f;
        float w5 = k5 ? (float)__ushort_as_half((unsigned short)(e5 >> 17)) : 0.f;
        float w6 = k6 ? (float)__ushort_as_half((unsigned short)(e6 >> 17)) : 0.f;
        float w7 = k7 ? (float)__ushort_as_half((unsigned short)(e7 >> 17)) : 0.f;
#pragma unroll
        for (int k = 0; k < 8; ++k) {
            float a = acc[k];
            a += w0 * (float)v0[k];
            a += w1 * (float)v1[k];
            a += w2 * (float)v2[k];
            a += w3 * (float)v3[k];
            a += w4 * (float)v4[k];
            a += w5 * (float)v5[k];
            a += w6 * (float)v6[k];
            a += w7 * (float)v7[k];
            acc[k] = a;
        }
    } else if (deg > 64) {                      // P ~ 3e-7: R16 fallback
        for (int j = off0; j < off1; j += 32) {
            int   i0 = j + g,      i1 = j + 8 + g,  i2 = j + 16 + g, i3 = j + 24 + g;
            bool  k0 = i0 < off1,  k1 = i1 < off1,  k2 = i2 < off1,  k3 = i3 < off1;
            unsigned eA = csr[k0 ? i0 : off1 - 1];
            unsigned eB = csr[k1 ? i1 : off1 - 1];
            unsigned eC = csr[k2 ? i2 : off1 - 1];
            unsigned eD = csr[k3 ? i3 : off1 - 1];
            f16x8 vA = *(const f16x8*)(hsB + ((eA & 0x1FFFFu) << 7) + sbyte);
            f16x8 vB = *(const f16x8*)(hsB + ((eB & 0x1FFFFu) << 7) + sbyte);
            f16x8 vC = *(const f16x8*)(hsB + ((eC & 0x1FFFFu) << 7) + sbyte);
            f16x8 vD = *(const f16x8*)(hsB + ((eD & 0x1FFFFu) << 7) + sbyte);
            float wA = k0 ? (float)__ushort_as_half((unsigned short)(eA >> 17)) : 0.f;
            float wB = k1 ? (float)__ushort_as_half((unsigned short)(eB >> 17)) : 0.f;
            float wC = k2 ? (float)__ushort_as_half((unsigned short)(eC >> 17)) : 0.f;
            float wD = k3 ? (float)__ushort_as_half((unsigned short)(eD >> 17)) : 0.f;
#pragma unroll
            for (int k = 0; k < 8; ++k) {
                acc[k] += wA * (float)vA[k];
                acc[k] += wB * (float)vB[k];
                acc[k] += wC * (float)vC[k];
                acc[k] += wD * (float)vD[k];
            }
        }
    }

    // reduce over groups (lane bits 3,4,5): DPP ror8 + swizzle xor16 + shfl32
#pragma unroll
    for (int k = 0; k < 8; ++k) {
        float t = acc[k];
        t += dpp_ror8(t);
        t += swz_xor16(t);
        t += __shfl_xor(t, 32);
        acc[k] = t;
    }

    float di = dinv[wid];
    float4 bA = ((const float4*)b1)[s * 2], bB = ((const float4*)b1)[s * 2 + 1];
    float4 wA = ((const float4*)W2)[s * 2], wB = ((const float4*)W2)[s * 2 + 1];
    float p = 0.f;
    p += fmaxf(di * acc[0] + bA.x, 0.f) * wA.x;
    p += fmaxf(di * acc[1] + bA.y, 0.f) * wA.y;
    p += fmaxf(di * acc[2] + bA.z, 0.f) * wA.z;
    p += fmaxf(di * acc[3] + bA.w, 0.f) * wA.w;
    p += fmaxf(di * acc[4] + bB.x, 0.f) * wB.x;
    p += fmaxf(di * acc[5] + bB.y, 0.f) * wB.y;
    p += fmaxf(di * acc[6] + bB.z, 0.f) * wB.z;
    p += fmaxf(di * acc[7] + bB.w, 0.f) * wB.w;
    // reduce over s (lane bits 0,1,2): pure DPP
    p += dpp_mov<0xB1>(p);    // quad_perm [1,0,3,2] == xor 1
    p += dpp_mov<0x4E>(p);    // quad_perm [2,3,0,1] == xor 2
    p += dpp_mov<0x141>(p);   // row_half_mirror == xor 4 after 1,2 reduced
    if (lane == 0) h2s[wid] = di * p;
}

// ---------------- agg2 (identical to R16) ----------------

__global__ __launch_bounds__(256) void k_agg2(const float* __restrict__ h2s,
                                              const int* __restrict__ offset,
                                              const unsigned* __restrict__ csr,
                                              const float* __restrict__ dinv,
                                              const float* __restrict__ b2,
                                              float* __restrict__ out, int n) {
    int wid = __builtin_amdgcn_readfirstlane((int)((blockIdx.x * blockDim.x + threadIdx.x) >> 6));
    int lane = threadIdx.x & 63;
    if (wid >= n) return;
    int off0 = __builtin_amdgcn_readfirstlane(offset[wid]);
    int off1 = __builtin_amdgcn_readfirstlane(offset[wid + 1]);
    float di = dinv[wid];
    float p = 0.f;
    for (int e = off0 + lane; e < off1; e += 64) {
        unsigned ed = csr[e];
        p += (float)__ushort_as_half((unsigned short)(ed >> 17)) * h2s[ed & 0x1FFFF];
    }
#pragma unroll
    for (int s = 32; s > 0; s >>= 1) p += __shfl_xor(p, s);
    if (lane == 0) out[wid] = di * (p + h2s[wid]) + b2[0];
}

extern "C" void kernel_launch(void* const* d_in, const int* in_sizes, int n_in,
                              void* d_out, int out_size, void* d_ws, size_t ws_size,
                              hipStream_t stream) {
    const float* x  = (const float*)d_in[0];
    const int*   ei = (const int*)  d_in[1];
    const float* ea = (const float*)d_in[2];
    const float* W1 = (const float*)d_in[3];
    const float* b1 = (const float*)d_in[4];
    const float* W2 = (const float*)d_in[5];
    const float* b2 = (const float*)d_in[6];
    float* out = (float*)d_out;

    const int N  = in_sizes[0] / 128;   // 100000 (must be <= 131072)
    const int E  = in_sizes[2];         // 3200000
    const int E4 = E / 4;
    const int nbl  = (E4 + 4095) / 4096;        // 16384-edge chunks (196)
    const int nbkt = (N + BSIZE - 1) / BSIZE;   // active buckets (196)

    char* p = (char*)d_ws;
    auto alloc = [&](size_t bytes) -> void* {
        void* r = (void*)p;
        p += (bytes + 255) & ~(size_t)255;
        return r;
    };
    int*       hist   = (int*)      alloc((size_t)nbl * NBUCKET * 4);
    int*       histS  = (int*)      alloc((size_t)NBUCKET * nbl * 4);
    int*       tot    = (int*)      alloc((size_t)NBUCKET * 4);
    int*       base   = (int*)      alloc((size_t)(NBUCKET + 1) * 4);
    int2*      binned = (int2*)     alloc((size_t)E * 8);
    unsigned*  csr    = (unsigned*) alloc((size_t)E * 4);
    int*       offset = (int*)      alloc((size_t)(N + 1) * 4);
    float*     dinv   = (float*)    alloc((size_t)N * 4);
    __half*    hs     = (__half*)   alloc((size_t)N * 64 * 2);
    float*     h2s    = (float*)    alloc((size_t)N * 4);

    const int nb_gemm = (N + 63) / 64;
    const int nb_wave = (N * 64 + 255) / 256;   // one 64-wide wave per node

    k_hist<<<nbl, 1024, 0, stream>>>(ei + E, hist, E4);
    k_scan_bucket<<<NBUCKET, 256, 0, stream>>>(hist, histS, tot, nbl);
    k_scan_tot<<<1, 256, 0, stream>>>(tot, base);
    k_scatter<<<nbl, 1024, 0, stream>>>(ei, ea, histS, base, binned, E, E4, nbl);
    k_finalize<<<nbkt, 1024, 0, stream>>>(binned, base, csr, offset, dinv, N, E);
    k_gemm_mfma<<<nb_gemm, 256, 0, stream>>>(x, W1, dinv, hs, N);
    k_agg1<<<nb_wave, 256, 0, stream>>>(hs, offset, csr, dinv, b1, W2, h2s, N);
    k_agg2<<<nb_wave, 256, 0, stream>>>(h2s, offset, csr, dinv, b2, out, N);
}

// Round 8
// 281.795 us; speedup vs baseline: 2.8709x; 1.0854x over previous
//
#include <hip/hip_runtime.h>
#include <hip/hip_fp16.h>

// ---------------------------------------------------------------------------
// GCN 2-layer (PyG GCNConv) on MI355X — R22.
// R21 post-mortem: 8-deep gather, clean (no spill, WRITE 0.78MB), still LOST
// (agg1 52->77us): VGPR 28->44 cut occupancy 67->49% and eff-BW 3.1->2.1TB/s.
// Dataset across R14/16/18/21: agg1 BW tracks (resident waves x issue rate),
// peaks at the lean R16 form; gathers already consume full 128B lines.
// LEDGER: agg1 frozen at R16 form (~52us, ~3.1TB/s on 157MB).
// R22 targets the ~235us build instead. Single structural delta:
//   k_hist + k_scan_bucket DELETED. k_scatter1 LDS-counts its chunk per
//   bucket, then reserves space with ONE global atomicAdd per bucket
//   (256/block, 50K total — vs R20's 12.8M random RMWs) into fixed-capacity
//   segments binned[b*CAP ..], CAP=18432 = mean+16sigma (unbreachable for
//   binomial bucket fill). Within-bucket order arbitrary (finalize re-sorts
//   anyway). 256-wide scan of final counts still yields global csr bases.
//   Col array read once instead of twice (-12.8MB); 8 launches -> 7.
// finalize/gemm/agg1/agg2 = byte-identical R16 bodies.
// Predict: total 287.5 -> ~272-278us; agg1 unchanged ~52 (top-5); absmax
// 9.77e-4. Failure: passed=false => CAP overflow; delta <5us => hist/scans
// were cheap => next round carves gemm/finalize/agg2.
// ---------------------------------------------------------------------------

#define BSHIFT 9
#define BSIZE 512            // nodes per bucket
#define NBUCKET 256          // max buckets (requires N <= 131072)
#define BCAP 18432           // bucket capacity: mean 16384 + 16 sigma

typedef _Float16 f16x8 __attribute__((ext_vector_type(8)));
typedef float    f32x4 __attribute__((ext_vector_type(4)));

// ---------------- CSR build (R22: reservation scatter) ----------------

__global__ __launch_bounds__(256) void k_z256(int* __restrict__ gcnt) {
    gcnt[threadIdx.x] = 0;
}

// One pass: LDS bucket count -> global reservation -> scatter into fixed
// bucket segments. 16384 edges per block, 1024 threads, 4 int4 per thread.
__global__ __launch_bounds__(1024) void k_scatter1(const int* __restrict__ ei,
                                                   const float* __restrict__ ea,
                                                   int* __restrict__ gcnt,
                                                   int2* __restrict__ binned,
                                                   int E, int E4) {
    __shared__ int cnt[NBUCKET];
    __shared__ int cur[NBUCKET];
    int t = threadIdx.x, bl = blockIdx.x;
    if (t < NBUCKET) cnt[t] = 0;
    __syncthreads();

    int4 c0, c1, c2, c3;
    bool v0, v1, v2, v3;
    {
        int idx0 = bl * 4096 + t;
        int idx1 = idx0 + 1024, idx2 = idx0 + 2048, idx3 = idx0 + 3072;
        v0 = idx0 < E4; v1 = idx1 < E4; v2 = idx2 < E4; v3 = idx3 < E4;
        const int4* colv = (const int4*)(ei + E);
        if (v0) { c0 = colv[idx0];
            atomicAdd(&cnt[c0.x >> BSHIFT], 1); atomicAdd(&cnt[c0.y >> BSHIFT], 1);
            atomicAdd(&cnt[c0.z >> BSHIFT], 1); atomicAdd(&cnt[c0.w >> BSHIFT], 1); }
        if (v1) { c1 = colv[idx1];
            atomicAdd(&cnt[c1.x >> BSHIFT], 1); atomicAdd(&cnt[c1.y >> BSHIFT], 1);
            atomicAdd(&cnt[c1.z >> BSHIFT], 1); atomicAdd(&cnt[c1.w >> BSHIFT], 1); }
        if (v2) { c2 = colv[idx2];
            atomicAdd(&cnt[c2.x >> BSHIFT], 1); atomicAdd(&cnt[c2.y >> BSHIFT], 1);
            atomicAdd(&cnt[c2.z >> BSHIFT], 1); atomicAdd(&cnt[c2.w >> BSHIFT], 1); }
        if (v3) { c3 = colv[idx3];
            atomicAdd(&cnt[c3.x >> BSHIFT], 1); atomicAdd(&cnt[c3.y >> BSHIFT], 1);
            atomicAdd(&cnt[c3.z >> BSHIFT], 1); atomicAdd(&cnt[c3.w >> BSHIFT], 1); }
    }
    __syncthreads();
    if (t < NBUCKET) cur[t] = t * BCAP + atomicAdd(&gcnt[t], cnt[t]);
    __syncthreads();

#define SCAT_ONE(cc, rr, ww)                                                  \
    {                                                                         \
        int p = atomicAdd(&cur[(cc) >> BSHIFT], 1);                           \
        binned[p] = make_int2((((cc) & (BSIZE - 1)) << 17) | (rr),            \
                              __float_as_int(ww));                            \
    }
#define SCAT_QUAD(cq, idx)                                                    \
    {                                                                         \
        int4   r = ((const int4*)ei)[idx];                                    \
        float4 w = ((const float4*)ea)[idx];                                  \
        SCAT_ONE(cq.x, r.x, w.x); SCAT_ONE(cq.y, r.y, w.y);                   \
        SCAT_ONE(cq.z, r.z, w.z); SCAT_ONE(cq.w, r.w, w.w);                   \
    }
    {
        int idx0 = bl * 4096 + t;
        if (v0) SCAT_QUAD(c0, idx0);
        if (v1) SCAT_QUAD(c1, idx0 + 1024);
        if (v2) SCAT_QUAD(c2, idx0 + 2048);
        if (v3) SCAT_QUAD(c3, idx0 + 3072);
    }
#undef SCAT_QUAD
#undef SCAT_ONE
}

// 1 block: exclusive scan of gcnt[256] -> base[256], base[NBUCKET] = E.
__global__ __launch_bounds__(256) void k_scan_base(const int* __restrict__ gcnt,
                                                   int* __restrict__ base) {
    __shared__ int A[2][NBUCKET];
    int t = threadIdx.x;
    A[0][t] = gcnt[t];
    __syncthreads();
    int src = 0;
    for (int off = 1; off < NBUCKET; off <<= 1) {
        A[1 - src][t] = A[src][t] + ((t >= off) ? A[src][t - off] : 0);
        src ^= 1;
        __syncthreads();
    }
    base[t] = (t > 0) ? A[src][t - 1] : 0;
    if (t == 255) base[NBUCKET] = A[src][255];
}

// R16 finalize body; binned segment now [b*BCAP, b*BCAP+gcnt[b]), csr base
// from scanned base[b]. Emits offset, dinv, csr.
__global__ __launch_bounds__(1024) void k_finalize(const int2* __restrict__ binned,
                                                   const int* __restrict__ gcnt,
                                                   const int* __restrict__ base,
                                                   unsigned* __restrict__ csr,
                                                   int* __restrict__ offset,
                                                   float* __restrict__ dinv,
                                                   int N, int E) {
    __shared__ int   cnt[BSIZE];
    __shared__ float fsum[BSIZE];
    __shared__ int   inc[2][BSIZE];
    __shared__ int   cur[BSIZE];
    int b = blockIdx.x, t = threadIdx.x;
    int e0 = b * BCAP;
    int e1 = e0 + gcnt[b];
    int c0 = base[b];
    for (int i = t; i < BSIZE; i += 1024) { cnt[i] = 0; fsum[i] = 0.f; }
    __syncthreads();
    for (int e = e0 + t; e < e1; e += 1024) {
        int2 ed = binned[e];
        unsigned cl = ((unsigned)ed.x) >> 17;
        atomicAdd(&cnt[cl], 1);
        atomicAdd(&fsum[cl], __int_as_float(ed.y));
    }
    __syncthreads();
    for (int i = t; i < BSIZE; i += 1024) inc[0][i] = cnt[i];
    __syncthreads();
    int src = 0;
    for (int off = 1; off < BSIZE; off <<= 1) {
        for (int i = t; i < BSIZE; i += 1024)
            inc[1 - src][i] = inc[src][i] + ((i >= off) ? inc[src][i - off] : 0);
        src ^= 1;
        __syncthreads();
    }
    int nodeBase = b << BSHIFT;
    for (int i = t; i < BSIZE; i += 1024) {
        int ex = (i > 0) ? inc[src][i - 1] : 0;
        cur[i] = c0 + ex;
        int node = nodeBase + i;
        if (node < N) {
            offset[node] = c0 + ex;
            dinv[node]   = rsqrtf(1.0f + fsum[i]);
        }
    }
    if (b == 0 && t == 0) offset[N] = E;
    __syncthreads();
    for (int e = e0 + t; e < e1; e += 1024) {
        int2 ed = binned[e];
        unsigned cl = ((unsigned)ed.x) >> 17;
        unsigned row = ((unsigned)ed.x) & 0x1FFFF;
        unsigned hb = (unsigned)__half_as_ushort(__float2half_rn(__int_as_float(ed.y))) & 0x7FFFu;
        int p = atomicAdd(&cur[cl], 1);
        csr[p] = (hb << 17) | row;
    }
}

// ---------------- dense compute (identical to R16) ----------------

__global__ __launch_bounds__(256) void k_gemm_mfma(const float* __restrict__ x,
                                                   const float* __restrict__ W1,
                                                   const float* __restrict__ dinv,
                                                   __half* __restrict__ hs, int n) {
    __shared__ _Float16 xh[64][136];
    __shared__ _Float16 wTh[64][136];
    int t = threadIdx.x;
    int nodeBase = blockIdx.x * 64;

    for (int i = t; i < 2048; i += 256) {
        int r = i >> 5, c4 = i & 31;
        int node = nodeBase + r;
        float4 v = make_float4(0.f, 0.f, 0.f, 0.f);
        if (node < n) v = ((const float4*)x)[node * 32 + c4];
        _Float16* dst = &xh[r][c4 * 4];
        dst[0] = (_Float16)v.x; dst[1] = (_Float16)v.y;
        dst[2] = (_Float16)v.z; dst[3] = (_Float16)v.w;
    }
    for (int i = t; i < 2048; i += 256) {
        int k = i >> 4, c4 = i & 15;
        float4 v = ((const float4*)W1)[k * 16 + c4];
        wTh[c4 * 4 + 0][k] = (_Float16)v.x;
        wTh[c4 * 4 + 1][k] = (_Float16)v.y;
        wTh[c4 * 4 + 2][k] = (_Float16)v.z;
        wTh[c4 * 4 + 3][k] = (_Float16)v.w;
    }
    __syncthreads();

    int w = t >> 6, lane = t & 63;
    int m = lane & 15, quad = lane >> 4;

    f32x4 acc[4] = {{0.f,0.f,0.f,0.f},{0.f,0.f,0.f,0.f},
                    {0.f,0.f,0.f,0.f},{0.f,0.f,0.f,0.f}};
#pragma unroll
    for (int ks = 0; ks < 128; ks += 32) {
        f16x8 a = *(const f16x8*)&xh[w * 16 + m][ks + quad * 8];
#pragma unroll
        for (int ct = 0; ct < 4; ++ct) {
            f16x8 bfr = *(const f16x8*)&wTh[ct * 16 + m][ks + quad * 8];
            acc[ct] = __builtin_amdgcn_mfma_f32_16x16x32_f16(a, bfr, acc[ct], 0, 0, 0);
        }
    }

#pragma unroll
    for (int reg = 0; reg < 4; ++reg) {
        int node = nodeBase + w * 16 + quad * 4 + reg;
        if (node < n) {
            float dv = dinv[node];
#pragma unroll
            for (int ct = 0; ct < 4; ++ct) {
                float v = acc[ct][reg] * dv;
                hs[(size_t)node * 64 + ct * 16 + m] = __float2half_rn(v);
            }
        }
    }
}

// ---------------- DPP reduce helpers (hardware-verified in R16) ----------

__device__ __forceinline__ float dpp_ror8(float x) {
    return __int_as_float(__builtin_amdgcn_update_dpp(
        0, __float_as_int(x), 0x128, 0xF, 0xF, true));
}
template<int CTRL>
__device__ __forceinline__ float dpp_mov(float x) {
    return __int_as_float(__builtin_amdgcn_update_dpp(
        0, __float_as_int(x), CTRL, 0xF, 0xF, true));
}
__device__ __forceinline__ float swz_xor16(float x) {
    return __int_as_float(__builtin_amdgcn_ds_swizzle(__float_as_int(x), 0x401F));
}

// ---------------- agg1 (frozen R16 form) ----------------

__global__ __launch_bounds__(256) void k_agg1(const __half* __restrict__ hs,
                                              const int* __restrict__ offset,
                                              const unsigned* __restrict__ csr,
                                              const float* __restrict__ dinv,
                                              const float* __restrict__ b1,
                                              const float* __restrict__ W2,
                                              float* __restrict__ h2s, int n) {
    int wid  = __builtin_amdgcn_readfirstlane(
                   (int)((blockIdx.x * blockDim.x + threadIdx.x) >> 6));
    int lane = threadIdx.x & 63;
    if (wid >= n) return;
    int off0 = __builtin_amdgcn_readfirstlane(offset[wid]);
    int off1 = __builtin_amdgcn_readfirstlane(offset[wid + 1]);
    int g = lane >> 3, s = lane & 7;
    unsigned sbyte = (unsigned)s << 4;          // s * 16 bytes
    const char* hsB = (const char*)hs;

    float acc[8] = {0.f, 0.f, 0.f, 0.f, 0.f, 0.f, 0.f, 0.f};

    {   // self loop (weight 1)
        f16x8 v = *(const f16x8*)(hsB + (((unsigned)wid) << 7) + sbyte);
        if (g == 0) {
#pragma unroll
            for (int k = 0; k < 8; ++k) acc[k] += (float)v[k];
        }
    }

    for (int j = off0; j < off1; j += 32) {
        int   i0 = j + g,      i1 = j + 8 + g,  i2 = j + 16 + g, i3 = j + 24 + g;
        bool  k0 = i0 < off1,  k1 = i1 < off1,  k2 = i2 < off1,  k3 = i3 < off1;
        unsigned eA = csr[k0 ? i0 : off1 - 1];
        unsigned eB = csr[k1 ? i1 : off1 - 1];
        unsigned eC = csr[k2 ? i2 : off1 - 1];
        unsigned eD = csr[k3 ? i3 : off1 - 1];
        f16x8 vA = *(const f16x8*)(hsB + ((eA & 0x1FFFFu) << 7) + sbyte);
        f16x8 vB = *(const f16x8*)(hsB + ((eB & 0x1FFFFu) << 7) + sbyte);
        f16x8 vC = *(const f16x8*)(hsB + ((eC & 0x1FFFFu) << 7) + sbyte);
        f16x8 vD = *(const f16x8*)(hsB + ((eD & 0x1FFFFu) << 7) + sbyte);
        float wA = k0 ? (float)__ushort_as_half((unsigned short)(eA >> 17)) : 0.f;
        float wB = k1 ? (float)__ushort_as_half((unsigned short)(eB >> 17)) : 0.f;
        float wC = k2 ? (float)__ushort_as_half((unsigned short)(eC >> 17)) : 0.f;
        float wD = k3 ? (float)__ushort_as_half((unsigned short)(eD >> 17)) : 0.f;
#pragma unroll
        for (int k = 0; k < 8; ++k) {
            acc[k] += wA * (float)vA[k];
            acc[k] += wB * (float)vB[k];
            acc[k] += wC * (float)vC[k];
            acc[k] += wD * (float)vD[k];
        }
    }

    // reduce over groups (lane bits 3,4,5): DPP ror8 + swizzle xor16 + shfl32
#pragma unroll
    for (int k = 0; k < 8; ++k) {
        float t = acc[k];
        t += dpp_ror8(t);
        t += swz_xor16(t);
        t += __shfl_xor(t, 32);
        acc[k] = t;
    }

    float di = dinv[wid];
    float4 bA = ((const float4*)b1)[s * 2], bB = ((const float4*)b1)[s * 2 + 1];
    float4 wA = ((const float4*)W2)[s * 2], wB = ((const float4*)W2)[s * 2 + 1];
    float p = 0.f;
    p += fmaxf(di * acc[0] + bA.x, 0.f) * wA.x;
    p += fmaxf(di * acc[1] + bA.y, 0.f) * wA.y;
    p += fmaxf(di * acc[2] + bA.z, 0.f) * wA.z;
    p += fmaxf(di * acc[3] + bA.w, 0.f) * wA.w;
    p += fmaxf(di * acc[4] + bB.x, 0.f) * wB.x;
    p += fmaxf(di * acc[5] + bB.y, 0.f) * wB.y;
    p += fmaxf(di * acc[6] + bB.z, 0.f) * wB.z;
    p += fmaxf(di * acc[7] + bB.w, 0.f) * wB.w;
    // reduce over s (lane bits 0,1,2): pure DPP
    p += dpp_mov<0xB1>(p);    // quad_perm [1,0,3,2] == xor 1
    p += dpp_mov<0x4E>(p);    // quad_perm [2,3,0,1] == xor 2
    p += dpp_mov<0x141>(p);   // row_half_mirror == xor 4 after 1,2 reduced
    if (lane == 0) h2s[wid] = di * p;
}

// ---------------- agg2 (identical to R16) ----------------

__global__ __launch_bounds__(256) void k_agg2(const float* __restrict__ h2s,
                                              const int* __restrict__ offset,
                                              const unsigned* __restrict__ csr,
                                              const float* __restrict__ dinv,
                                              const float* __restrict__ b2,
                                              float* __restrict__ out, int n) {
    int wid = __builtin_amdgcn_readfirstlane((int)((blockIdx.x * blockDim.x + threadIdx.x) >> 6));
    int lane = threadIdx.x & 63;
    if (wid >= n) return;
    int off0 = __builtin_amdgcn_readfirstlane(offset[wid]);
    int off1 = __builtin_amdgcn_readfirstlane(offset[wid + 1]);
    float di = dinv[wid];
    float p = 0.f;
    for (int e = off0 + lane; e < off1; e += 64) {
        unsigned ed = csr[e];
        p += (float)__ushort_as_half((unsigned short)(ed >> 17)) * h2s[ed & 0x1FFFF];
    }
#pragma unroll
    for (int s = 32; s > 0; s >>= 1) p += __shfl_xor(p, s);
    if (lane == 0) out[wid] = di * (p + h2s[wid]) + b2[0];
}

extern "C" void kernel_launch(void* const* d_in, const int* in_sizes, int n_in,
                              void* d_out, int out_size, void* d_ws, size_t ws_size,
                              hipStream_t stream) {
    const float* x  = (const float*)d_in[0];
    const int*   ei = (const int*)  d_in[1];
    const float* ea = (const float*)d_in[2];
    const float* W1 = (const float*)d_in[3];
    const float* b1 = (const float*)d_in[4];
    const float* W2 = (const float*)d_in[5];
    const float* b2 = (const float*)d_in[6];
    float* out = (float*)d_out;

    const int N  = in_sizes[0] / 128;   // 100000 (must be <= 131072)
    const int E  = in_sizes[2];         // 3200000
    const int E4 = E / 4;
    const int nbl  = (E4 + 4095) / 4096;        // 16384-edge chunks (196)
    const int nbkt = (N + BSIZE - 1) / BSIZE;   // active buckets (196)

    char* p = (char*)d_ws;
    auto alloc = [&](size_t bytes) -> void* {
        void* r = (void*)p;
        p += (bytes + 255) & ~(size_t)255;
        return r;
    };
    int*       gcnt   = (int*)      alloc((size_t)NBUCKET * 4);
    int*       base   = (int*)      alloc((size_t)(NBUCKET + 1) * 4);
    int2*      binned = (int2*)     alloc((size_t)NBUCKET * BCAP * 8);  // 37.7MB
    unsigned*  csr    = (unsigned*) alloc((size_t)E * 4);
    int*       offset = (int*)      alloc((size_t)(N + 1) * 4);
    float*     dinv   = (float*)    alloc((size_t)N * 4);
    __half*    hs     = (__half*)   alloc((size_t)N * 64 * 2);
    float*     h2s    = (float*)    alloc((size_t)N * 4);

    const int nb_gemm = (N + 63) / 64;
    const int nb_wave = (N * 64 + 255) / 256;   // one 64-wide wave per node

    k_z256<<<1, 256, 0, stream>>>(gcnt);
    k_scatter1<<<nbl, 1024, 0, stream>>>(ei, ea, gcnt, binned, E, E4);
    k_scan_base<<<1, 256, 0, stream>>>(gcnt, base);
    k_finalize<<<nbkt, 1024, 0, stream>>>(binned, gcnt, base, csr, offset, dinv, N, E);
    k_gemm_mfma<<<nb_gemm, 256, 0, stream>>>(x, W1, dinv, hs, N);
    k_agg1<<<nb_wave, 256, 0, stream>>>(hs, offset, csr, dinv, b1, W2, h2s, N);
    k_agg2<<<nb_wave, 256, 0, stream>>>(h2s, offset, csr, dinv, b2, out, N);
}

// Round 9
// 279.622 us; speedup vs baseline: 2.8932x; 1.0078x over previous
//
#include <hip/hip_runtime.h>
#include <hip/hip_fp16.h>

// ---------------------------------------------------------------------------
// GCN 2-layer (PyG GCNConv) on MI355X — R23.
// R22 post-mortem: reservation scatter landed (287.5 -> 281.8 best). All
// non-agg1 kernels bounded <53us by top-5, but sum to ~228us -> build-phase
// eff BW ~1.5TB/s. Biggest structural waste: k_finalize streams binned
// (25.6MB) TWICE (count pass + emit pass) and k_scan_base is a whole launch
// for a 256-wide scan.
// R23 single change-unit (finalize restructure; all else byte-identical):
//   (1) LDS edge cache: pass A reads each binned entry ONCE, stores it in a
//       147KB LDS buffer while counting cnt/fsum; emit pass reads LDS.
//       Free parallelism-wise: grid 196 < 256 CUs -> every block co-resident
//       regardless of LDS (16 waves/CU either way). gfx950 static LDS >64KB
//       proven by R17 (128KB ran). Total static LDS 159.7KB <= 160KB.
//   (2) inline gcnt scan per block (sG[2][256], 8 steps) -> k_scan_base
//       deleted; 7 -> 6 launches.
// Predict: total 281.8 -> ~264-270us; agg1 unchanged ~53 / 157MB; absmax
// exactly 9.766e-4 (bit-identical arithmetic).
// Failure: (a) LDS compile/launch fail -> shrink cache, restore scan kernel;
// (b) delta <5us -> finalize latency-bound -> split count phase next.
// ---------------------------------------------------------------------------

#define BSHIFT 9
#define BSIZE 512            // nodes per bucket
#define NBUCKET 256          // max buckets (requires N <= 131072)
#define BCAP 18432           // bucket capacity: mean 16384 + 16 sigma

typedef _Float16 f16x8 __attribute__((ext_vector_type(8)));
typedef float    f32x4 __attribute__((ext_vector_type(4)));

// ---------------- CSR build (R22 reservation scatter) ----------------

__global__ __launch_bounds__(256) void k_z256(int* __restrict__ gcnt) {
    gcnt[threadIdx.x] = 0;
}

// One pass: LDS bucket count -> global reservation -> scatter into fixed
// bucket segments. 16384 edges per block, 1024 threads, 4 int4 per thread.
__global__ __launch_bounds__(1024) void k_scatter1(const int* __restrict__ ei,
                                                   const float* __restrict__ ea,
                                                   int* __restrict__ gcnt,
                                                   int2* __restrict__ binned,
                                                   int E, int E4) {
    __shared__ int cnt[NBUCKET];
    __shared__ int cur[NBUCKET];
    int t = threadIdx.x, bl = blockIdx.x;
    if (t < NBUCKET) cnt[t] = 0;
    __syncthreads();

    int4 c0, c1, c2, c3;
    bool v0, v1, v2, v3;
    {
        int idx0 = bl * 4096 + t;
        int idx1 = idx0 + 1024, idx2 = idx0 + 2048, idx3 = idx0 + 3072;
        v0 = idx0 < E4; v1 = idx1 < E4; v2 = idx2 < E4; v3 = idx3 < E4;
        const int4* colv = (const int4*)(ei + E);
        if (v0) { c0 = colv[idx0];
            atomicAdd(&cnt[c0.x >> BSHIFT], 1); atomicAdd(&cnt[c0.y >> BSHIFT], 1);
            atomicAdd(&cnt[c0.z >> BSHIFT], 1); atomicAdd(&cnt[c0.w >> BSHIFT], 1); }
        if (v1) { c1 = colv[idx1];
            atomicAdd(&cnt[c1.x >> BSHIFT], 1); atomicAdd(&cnt[c1.y >> BSHIFT], 1);
            atomicAdd(&cnt[c1.z >> BSHIFT], 1); atomicAdd(&cnt[c1.w >> BSHIFT], 1); }
        if (v2) { c2 = colv[idx2];
            atomicAdd(&cnt[c2.x >> BSHIFT], 1); atomicAdd(&cnt[c2.y >> BSHIFT], 1);
            atomicAdd(&cnt[c2.z >> BSHIFT], 1); atomicAdd(&cnt[c2.w >> BSHIFT], 1); }
        if (v3) { c3 = colv[idx3];
            atomicAdd(&cnt[c3.x >> BSHIFT], 1); atomicAdd(&cnt[c3.y >> BSHIFT], 1);
            atomicAdd(&cnt[c3.z >> BSHIFT], 1); atomicAdd(&cnt[c3.w >> BSHIFT], 1); }
    }
    __syncthreads();
    if (t < NBUCKET) cur[t] = t * BCAP + atomicAdd(&gcnt[t], cnt[t]);
    __syncthreads();

#define SCAT_ONE(cc, rr, ww)                                                  \
    {                                                                         \
        int p = atomicAdd(&cur[(cc) >> BSHIFT], 1);                           \
        binned[p] = make_int2((((cc) & (BSIZE - 1)) << 17) | (rr),            \
                              __float_as_int(ww));                            \
    }
#define SCAT_QUAD(cq, idx)                                                    \
    {                                                                         \
        int4   r = ((const int4*)ei)[idx];                                    \
        float4 w = ((const float4*)ea)[idx];                                  \
        SCAT_ONE(cq.x, r.x, w.x); SCAT_ONE(cq.y, r.y, w.y);                   \
        SCAT_ONE(cq.z, r.z, w.z); SCAT_ONE(cq.w, r.w, w.w);                   \
    }
    {
        int idx0 = bl * 4096 + t;
        if (v0) SCAT_QUAD(c0, idx0);
        if (v1) SCAT_QUAD(c1, idx0 + 1024);
        if (v2) SCAT_QUAD(c2, idx0 + 2048);
        if (v3) SCAT_QUAD(c3, idx0 + 3072);
    }
#undef SCAT_QUAD
#undef SCAT_ONE
}

// R23 finalize: inline gcnt scan + LDS edge cache (binned read ONCE).
// Static LDS: 147456 + 2048 + 2048 + 4096 + 2048 + 2048 = 159744 B <= 160KB.
__global__ __launch_bounds__(1024) void k_finalize(const int2* __restrict__ binned,
                                                   const int* __restrict__ gcnt,
                                                   unsigned* __restrict__ csr,
                                                   int* __restrict__ offset,
                                                   float* __restrict__ dinv,
                                                   int N, int E) {
    __shared__ int2  eL[BCAP];            // 147456 B edge cache
    __shared__ int   cnt[BSIZE];
    __shared__ float fsum[BSIZE];
    __shared__ int   inc[2][BSIZE];
    __shared__ int   cur[BSIZE];
    __shared__ int   sG[2][NBUCKET];
    int b = blockIdx.x, t = threadIdx.x;
    int ne = gcnt[b];
    int e0 = b * BCAP;

    if (t < NBUCKET) sG[0][t] = gcnt[t];
    for (int i = t; i < BSIZE; i += 1024) { cnt[i] = 0; fsum[i] = 0.f; }
    __syncthreads();
    int src = 0;
    for (int off = 1; off < NBUCKET; off <<= 1) {
        if (t < NBUCKET)
            sG[1 - src][t] = sG[src][t] + ((t >= off) ? sG[src][t - off] : 0);
        src ^= 1;
        __syncthreads();
    }
    int c0 = (b > 0) ? sG[src][b - 1] : 0;   // csr base for this bucket

    // pass A: single global read of this bucket's edges; cache + count
    for (int i = t; i < ne; i += 1024) {
        int2 ed = binned[e0 + i];
        eL[i] = ed;
        unsigned cl = ((unsigned)ed.x) >> 17;
        atomicAdd(&cnt[cl], 1);
        atomicAdd(&fsum[cl], __int_as_float(ed.y));
    }
    __syncthreads();

    // pass B: scan per-node counts
    for (int i = t; i < BSIZE; i += 1024) inc[0][i] = cnt[i];
    __syncthreads();
    src = 0;
    for (int off = 1; off < BSIZE; off <<= 1) {
        for (int i = t; i < BSIZE; i += 1024)
            inc[1 - src][i] = inc[src][i] + ((i >= off) ? inc[src][i - off] : 0);
        src ^= 1;
        __syncthreads();
    }
    int nodeBase = b << BSHIFT;
    for (int i = t; i < BSIZE; i += 1024) {
        int ex = (i > 0) ? inc[src][i - 1] : 0;
        cur[i] = c0 + ex;
        int node = nodeBase + i;
        if (node < N) {
            offset[node] = c0 + ex;
            dinv[node]   = rsqrtf(1.0f + fsum[i]);
        }
    }
    if (b == 0 && t == 0) offset[N] = E;
    __syncthreads();

    // pass C: emit csr from LDS (no global re-read)
    for (int i = t; i < ne; i += 1024) {
        int2 ed = eL[i];
        unsigned cl = ((unsigned)ed.x) >> 17;
        unsigned row = ((unsigned)ed.x) & 0x1FFFF;
        unsigned hb = (unsigned)__half_as_ushort(__float2half_rn(__int_as_float(ed.y))) & 0x7FFFu;
        int p = atomicAdd(&cur[cl], 1);
        csr[p] = (hb << 17) | row;
    }
}

// ---------------- dense compute (identical to R16/R22) ----------------

__global__ __launch_bounds__(256) void k_gemm_mfma(const float* __restrict__ x,
                                                   const float* __restrict__ W1,
                                                   const float* __restrict__ dinv,
                                                   __half* __restrict__ hs, int n) {
    __shared__ _Float16 xh[64][136];
    __shared__ _Float16 wTh[64][136];
    int t = threadIdx.x;
    int nodeBase = blockIdx.x * 64;

    for (int i = t; i < 2048; i += 256) {
        int r = i >> 5, c4 = i & 31;
        int node = nodeBase + r;
        float4 v = make_float4(0.f, 0.f, 0.f, 0.f);
        if (node < n) v = ((const float4*)x)[node * 32 + c4];
        _Float16* dst = &xh[r][c4 * 4];
        dst[0] = (_Float16)v.x; dst[1] = (_Float16)v.y;
        dst[2] = (_Float16)v.z; dst[3] = (_Float16)v.w;
    }
    for (int i = t; i < 2048; i += 256) {
        int k = i >> 4, c4 = i & 15;
        float4 v = ((const float4*)W1)[k * 16 + c4];
        wTh[c4 * 4 + 0][k] = (_Float16)v.x;
        wTh[c4 * 4 + 1][k] = (_Float16)v.y;
        wTh[c4 * 4 + 2][k] = (_Float16)v.z;
        wTh[c4 * 4 + 3][k] = (_Float16)v.w;
    }
    __syncthreads();

    int w = t >> 6, lane = t & 63;
    int m = lane & 15, quad = lane >> 4;

    f32x4 acc[4] = {{0.f,0.f,0.f,0.f},{0.f,0.f,0.f,0.f},
                    {0.f,0.f,0.f,0.f},{0.f,0.f,0.f,0.f}};
#pragma unroll
    for (int ks = 0; ks < 128; ks += 32) {
        f16x8 a = *(const f16x8*)&xh[w * 16 + m][ks + quad * 8];
#pragma unroll
        for (int ct = 0; ct < 4; ++ct) {
            f16x8 bfr = *(const f16x8*)&wTh[ct * 16 + m][ks + quad * 8];
            acc[ct] = __builtin_amdgcn_mfma_f32_16x16x32_f16(a, bfr, acc[ct], 0, 0, 0);
        }
    }

#pragma unroll
    for (int reg = 0; reg < 4; ++reg) {
        int node = nodeBase + w * 16 + quad * 4 + reg;
        if (node < n) {
            float dv = dinv[node];
#pragma unroll
            for (int ct = 0; ct < 4; ++ct) {
                float v = acc[ct][reg] * dv;
                hs[(size_t)node * 64 + ct * 16 + m] = __float2half_rn(v);
            }
        }
    }
}

// ---------------- DPP reduce helpers (hardware-verified in R16) ----------

__device__ __forceinline__ float dpp_ror8(float x) {
    return __int_as_float(__builtin_amdgcn_update_dpp(
        0, __float_as_int(x), 0x128, 0xF, 0xF, true));
}
template<int CTRL>
__device__ __forceinline__ float dpp_mov(float x) {
    return __int_as_float(__builtin_amdgcn_update_dpp(
        0, __float_as_int(x), CTRL, 0xF, 0xF, true));
}
__device__ __forceinline__ float swz_xor16(float x) {
    return __int_as_float(__builtin_amdgcn_ds_swizzle(__float_as_int(x), 0x401F));
}

// ---------------- agg1 (frozen R16 form) ----------------

__global__ __launch_bounds__(256) void k_agg1(const __half* __restrict__ hs,
                                              const int* __restrict__ offset,
                                              const unsigned* __restrict__ csr,
                                              const float* __restrict__ dinv,
                                              const float* __restrict__ b1,
                                              const float* __restrict__ W2,
                                              float* __restrict__ h2s, int n) {
    int wid  = __builtin_amdgcn_readfirstlane(
                   (int)((blockIdx.x * blockDim.x + threadIdx.x) >> 6));
    int lane = threadIdx.x & 63;
    if (wid >= n) return;
    int off0 = __builtin_amdgcn_readfirstlane(offset[wid]);
    int off1 = __builtin_amdgcn_readfirstlane(offset[wid + 1]);
    int g = lane >> 3, s = lane & 7;
    unsigned sbyte = (unsigned)s << 4;          // s * 16 bytes
    const char* hsB = (const char*)hs;

    float acc[8] = {0.f, 0.f, 0.f, 0.f, 0.f, 0.f, 0.f, 0.f};

    {   // self loop (weight 1)
        f16x8 v = *(const f16x8*)(hsB + (((unsigned)wid) << 7) + sbyte);
        if (g == 0) {
#pragma unroll
            for (int k = 0; k < 8; ++k) acc[k] += (float)v[k];
        }
    }

    for (int j = off0; j < off1; j += 32) {
        int   i0 = j + g,      i1 = j + 8 + g,  i2 = j + 16 + g, i3 = j + 24 + g;
        bool  k0 = i0 < off1,  k1 = i1 < off1,  k2 = i2 < off1,  k3 = i3 < off1;
        unsigned eA = csr[k0 ? i0 : off1 - 1];
        unsigned eB = csr[k1 ? i1 : off1 - 1];
        unsigned eC = csr[k2 ? i2 : off1 - 1];
        unsigned eD = csr[k3 ? i3 : off1 - 1];
        f16x8 vA = *(const f16x8*)(hsB + ((eA & 0x1FFFFu) << 7) + sbyte);
        f16x8 vB = *(const f16x8*)(hsB + ((eB & 0x1FFFFu) << 7) + sbyte);
        f16x8 vC = *(const f16x8*)(hsB + ((eC & 0x1FFFFu) << 7) + sbyte);
        f16x8 vD = *(const f16x8*)(hsB + ((eD & 0x1FFFFu) << 7) + sbyte);
        float wA = k0 ? (float)__ushort_as_half((unsigned short)(eA >> 17)) : 0.f;
        float wB = k1 ? (float)__ushort_as_half((unsigned short)(eB >> 17)) : 0.f;
        float wC = k2 ? (float)__ushort_as_half((unsigned short)(eC >> 17)) : 0.f;
        float wD = k3 ? (float)__ushort_as_half((unsigned short)(eD >> 17)) : 0.f;
#pragma unroll
        for (int k = 0; k < 8; ++k) {
            acc[k] += wA * (float)vA[k];
            acc[k] += wB * (float)vB[k];
            acc[k] += wC * (float)vC[k];
            acc[k] += wD * (float)vD[k];
        }
    }

    // reduce over groups (lane bits 3,4,5): DPP ror8 + swizzle xor16 + shfl32
#pragma unroll
    for (int k = 0; k < 8; ++k) {
        float t = acc[k];
        t += dpp_ror8(t);
        t += swz_xor16(t);
        t += __shfl_xor(t, 32);
        acc[k] = t;
    }

    float di = dinv[wid];
    float4 bA = ((const float4*)b1)[s * 2], bB = ((const float4*)b1)[s * 2 + 1];
    float4 wA = ((const float4*)W2)[s * 2], wB = ((const float4*)W2)[s * 2 + 1];
    float p = 0.f;
    p += fmaxf(di * acc[0] + bA.x, 0.f) * wA.x;
    p += fmaxf(di * acc[1] + bA.y, 0.f) * wA.y;
    p += fmaxf(di * acc[2] + bA.z, 0.f) * wA.z;
    p += fmaxf(di * acc[3] + bA.w, 0.f) * wA.w;
    p += fmaxf(di * acc[4] + bB.x, 0.f) * wB.x;
    p += fmaxf(di * acc[5] + bB.y, 0.f) * wB.y;
    p += fmaxf(di * acc[6] + bB.z, 0.f) * wB.z;
    p += fmaxf(di * acc[7] + bB.w, 0.f) * wB.w;
    // reduce over s (lane bits 0,1,2): pure DPP
    p += dpp_mov<0xB1>(p);    // quad_perm [1,0,3,2] == xor 1
    p += dpp_mov<0x4E>(p);    // quad_perm [2,3,0,1] == xor 2
    p += dpp_mov<0x141>(p);   // row_half_mirror == xor 4 after 1,2 reduced
    if (lane == 0) h2s[wid] = di * p;
}

// ---------------- agg2 (identical to R16) ----------------

__global__ __launch_bounds__(256) void k_agg2(const float* __restrict__ h2s,
                                              const int* __restrict__ offset,
                                              const unsigned* __restrict__ csr,
                                              const float* __restrict__ dinv,
                                              const float* __restrict__ b2,
                                              float* __restrict__ out, int n) {
    int wid = __builtin_amdgcn_readfirstlane((int)((blockIdx.x * blockDim.x + threadIdx.x) >> 6));
    int lane = threadIdx.x & 63;
    if (wid >= n) return;
    int off0 = __builtin_amdgcn_readfirstlane(offset[wid]);
    int off1 = __builtin_amdgcn_readfirstlane(offset[wid + 1]);
    float di = dinv[wid];
    float p = 0.f;
    for (int e = off0 + lane; e < off1; e += 64) {
        unsigned ed = csr[e];
        p += (float)__ushort_as_half((unsigned short)(ed >> 17)) * h2s[ed & 0x1FFFF];
    }
#pragma unroll
    for (int s = 32; s > 0; s >>= 1) p += __shfl_xor(p, s);
    if (lane == 0) out[wid] = di * (p + h2s[wid]) + b2[0];
}

extern "C" void kernel_launch(void* const* d_in, const int* in_sizes, int n_in,
                              void* d_out, int out_size, void* d_ws, size_t ws_size,
                              hipStream_t stream) {
    const float* x  = (const float*)d_in[0];
    const int*   ei = (const int*)  d_in[1];
    const float* ea = (const float*)d_in[2];
    const float* W1 = (const float*)d_in[3];
    const float* b1 = (const float*)d_in[4];
    const float* W2 = (const float*)d_in[5];
    const float* b2 = (const float*)d_in[6];
    float* out = (float*)d_out;

    const int N  = in_sizes[0] / 128;   // 100000 (must be <= 131072)
    const int E  = in_sizes[2];         // 3200000
    const int E4 = E / 4;
    const int nbl  = (E4 + 4095) / 4096;        // 16384-edge chunks (196)
    const int nbkt = (N + BSIZE - 1) / BSIZE;   // active buckets (196)

    char* p = (char*)d_ws;
    auto alloc = [&](size_t bytes) -> void* {
        void* r = (void*)p;
        p += (bytes + 255) & ~(size_t)255;
        return r;
    };
    int*       gcnt   = (int*)      alloc((size_t)NBUCKET * 4);
    int2*      binned = (int2*)     alloc((size_t)NBUCKET * BCAP * 8);  // 37.7MB
    unsigned*  csr    = (unsigned*) alloc((size_t)E * 4);
    int*       offset = (int*)      alloc((size_t)(N + 1) * 4);
    float*     dinv   = (float*)    alloc((size_t)N * 4);
    __half*    hs     = (__half*)   alloc((size_t)N * 64 * 2);
    float*     h2s    = (float*)    alloc((size_t)N * 4);

    const int nb_gemm = (N + 63) / 64;
    const int nb_wave = (N * 64 + 255) / 256;   // one 64-wide wave per node

    k_z256<<<1, 256, 0, stream>>>(gcnt);
    k_scatter1<<<nbl, 1024, 0, stream>>>(ei, ea, gcnt, binned, E, E4);
    k_finalize<<<nbkt, 1024, 0, stream>>>(binned, gcnt, csr, offset, dinv, N, E);
    k_gemm_mfma<<<nb_gemm, 256, 0, stream>>>(x, W1, dinv, hs, N);
    k_agg1<<<nb_wave, 256, 0, stream>>>(hs, offset, csr, dinv, b1, W2, h2s, N);
    k_agg2<<<nb_wave, 256, 0, stream>>>(h2s, offset, csr, dinv, b2, out, N);
}